// Round 1
// baseline (3288.077 us; speedup 1.0000x reference)
//
#include <hip/hip_runtime.h>
#include <math.h>

// Problem constants (from reference): B=4, S=2048, E=1024, H=16, D=64
constexpr int Bn = 4;
constexpr int Sn = 2048;
constexpr int En = 1024;
constexpr int Hn = 16;
constexpr int Dn = 64;

// ---------------------------------------------------------------------------
// Kernel 1: QKV projection.
// For each (b, h, proj): out[s,d] = sum_e x[b,s,e] * W[h,e,d] + bias[h,d]
// Grid: (S/64, H, B*3). Block 256 threads, 64x64 output tile, 4x4 micro-tile.
// ---------------------------------------------------------------------------
__global__ __launch_bounds__(256) void qkv_kernel(
    const float* __restrict__ x,
    const float* __restrict__ Wq, const float* __restrict__ bq,
    const float* __restrict__ Wk, const float* __restrict__ bk,
    const float* __restrict__ Wv, const float* __restrict__ bv,
    float* __restrict__ Qo, float* __restrict__ Ko, float* __restrict__ Vo)
{
    const int stile = blockIdx.x;   // 0..31
    const int h     = blockIdx.y;   // 0..15
    const int bz    = blockIdx.z;   // 0..11
    const int b = bz / 3, p = bz % 3;

    const float* W;
    const float* bias;
    float* out;
    if (p == 0)      { W = Wq; bias = bq; out = Qo; }
    else if (p == 1) { W = Wk; bias = bk; out = Ko; }
    else             { W = Wv; bias = bv; out = Vo; }
    W    += (size_t)h * En * Dn;                 // [E, D]
    bias += (size_t)h * Dn;                      // [D]
    out  += ((size_t)(b * Hn + h)) * Sn * Dn;    // [S, D]
    const float* xb = x + (size_t)b * Sn * En + (size_t)stile * 64 * En;

    __shared__ float As[64][33];  // x tile: 64 s x 32 e (+1 pad)
    __shared__ float Bs[32][65];  // W tile: 32 e x 64 d (+1 pad)

    const int tid = threadIdx.x;
    const int tx = tid % 16, ty = tid / 16;

    float acc[4][4] = {};

    for (int k0 = 0; k0 < En; k0 += 32) {
        // load x tile (coalesced along e)
        #pragma unroll
        for (int i = 0; i < 8; i++) {
            int idx = tid + i * 256;
            int r = idx / 32, c = idx % 32;
            As[r][c] = xb[(size_t)r * En + k0 + c];
        }
        // load W tile (coalesced along d)
        #pragma unroll
        for (int i = 0; i < 8; i++) {
            int idx = tid + i * 256;
            int r = idx / 64, c = idx % 64;
            Bs[r][c] = W[(size_t)(k0 + r) * Dn + c];
        }
        __syncthreads();
        #pragma unroll
        for (int k = 0; k < 32; k++) {
            float a[4], bb[4];
            #pragma unroll
            for (int i = 0; i < 4; i++) a[i] = As[ty * 4 + i][k];
            #pragma unroll
            for (int j = 0; j < 4; j++) bb[j] = Bs[k][tx * 4 + j];
            #pragma unroll
            for (int i = 0; i < 4; i++)
                #pragma unroll
                for (int j = 0; j < 4; j++)
                    acc[i][j] += a[i] * bb[j];
        }
        __syncthreads();
    }

    #pragma unroll
    for (int i = 0; i < 4; i++) {
        int r = ty * 4 + i;
        #pragma unroll
        for (int j = 0; j < 4; j++) {
            int c = tx * 4 + j;
            out[(size_t)(stile * 64 + r) * Dn + c] = acc[i][j] + bias[c];
        }
    }
}

// ---------------------------------------------------------------------------
// Kernel 2: causal flash attention (fp32).
// One block per (b*h, q-tile of 64). Block 256 threads.
// Online softmax with running m, l per query row.
// ---------------------------------------------------------------------------
__global__ __launch_bounds__(256) void attn_kernel(
    const float* __restrict__ Q, const float* __restrict__ K,
    const float* __restrict__ V, float* __restrict__ O)
{
    const int qtile = blockIdx.x;   // 0..31
    const int bh    = blockIdx.y;   // 0..63
    const float* Qp = Q + ((size_t)bh * Sn + (size_t)qtile * 64) * Dn;
    const float* Kp = K + (size_t)bh * Sn * Dn;
    const float* Vp = V + (size_t)bh * Sn * Dn;
    float*       Op = O + ((size_t)bh * Sn + (size_t)qtile * 64) * Dn;

    __shared__ float Qs[64][65];
    __shared__ float Ks[64][65];
    __shared__ float Vs[64][65];
    __shared__ float Ps[64][65];
    __shared__ float m_sh[64], l_sh[64], alpha_sh[64];

    const int tid = threadIdx.x;
    const int tx = tid % 16, ty = tid / 16;
    const float scale = 0.125f;  // 1/sqrt(64)

    // load Q tile
    #pragma unroll
    for (int i = 0; i < 16; i++) {
        int idx = tid + i * 256;
        int r = idx / 64, c = idx % 64;
        Qs[r][c] = Qp[(size_t)r * Dn + c];
    }
    if (tid < 64) { m_sh[tid] = -1e30f; l_sh[tid] = 0.f; }
    float acc[4][4] = {};
    __syncthreads();

    for (int kt = 0; kt <= qtile; kt++) {
        const float* Kt = Kp + (size_t)kt * 64 * Dn;
        const float* Vt = Vp + (size_t)kt * 64 * Dn;
        #pragma unroll
        for (int i = 0; i < 16; i++) {
            int idx = tid + i * 256;
            int r = idx / 64, c = idx % 64;
            Ks[r][c] = Kt[(size_t)r * Dn + c];
            Vs[r][c] = Vt[(size_t)r * Dn + c];
        }
        __syncthreads();

        // scores: S[i][j] = scale * sum_d Q[i][d]*K[j][d]
        float sacc[4][4] = {};
        #pragma unroll
        for (int d = 0; d < 64; d++) {
            float a[4], bb[4];
            #pragma unroll
            for (int i = 0; i < 4; i++) a[i] = Qs[ty * 4 + i][d];
            #pragma unroll
            for (int j = 0; j < 4; j++) bb[j] = Ks[tx * 4 + j][d];
            #pragma unroll
            for (int i = 0; i < 4; i++)
                #pragma unroll
                for (int j = 0; j < 4; j++)
                    sacc[i][j] += a[i] * bb[j];
        }
        const bool diag = (kt == qtile);
        #pragma unroll
        for (int i = 0; i < 4; i++) {
            #pragma unroll
            for (int j = 0; j < 4; j++) {
                float v = sacc[i][j] * scale;
                if (diag && (tx * 4 + j) > (ty * 4 + i)) v = -1e30f;
                Ps[ty * 4 + i][tx * 4 + j] = v;
            }
        }
        __syncthreads();

        // online softmax per row (threads 0..63, one row each)
        if (tid < 64) {
            float m_old = m_sh[tid];
            float rowmax = m_old;
            #pragma unroll 8
            for (int j = 0; j < 64; j++) rowmax = fmaxf(rowmax, Ps[tid][j]);
            float alpha = __expf(m_old - rowmax);
            float rs = 0.f;
            #pragma unroll 8
            for (int j = 0; j < 64; j++) {
                float pp = __expf(Ps[tid][j] - rowmax);
                Ps[tid][j] = pp;
                rs += pp;
            }
            m_sh[tid]     = rowmax;
            l_sh[tid]     = l_sh[tid] * alpha + rs;
            alpha_sh[tid] = alpha;
        }
        __syncthreads();

        // O = O*alpha + P@V
        float al[4];
        #pragma unroll
        for (int i = 0; i < 4; i++) al[i] = alpha_sh[ty * 4 + i];
        #pragma unroll
        for (int i = 0; i < 4; i++)
            #pragma unroll
            for (int j = 0; j < 4; j++) acc[i][j] *= al[i];
        #pragma unroll
        for (int k = 0; k < 64; k++) {
            float a[4], bb[4];
            #pragma unroll
            for (int i = 0; i < 4; i++) a[i] = Ps[ty * 4 + i][k];
            #pragma unroll
            for (int j = 0; j < 4; j++) bb[j] = Vs[k][tx * 4 + j];
            #pragma unroll
            for (int i = 0; i < 4; i++)
                #pragma unroll
                for (int j = 0; j < 4; j++)
                    acc[i][j] += a[i] * bb[j];
        }
        __syncthreads();
    }

    // normalize and write ctx [B,H,S,D]
    #pragma unroll
    for (int i = 0; i < 4; i++) {
        int r = ty * 4 + i;
        float inv = 1.f / l_sh[r];
        #pragma unroll
        for (int j = 0; j < 4; j++) {
            Op[(size_t)r * Dn + tx * 4 + j] = acc[i][j] * inv;
        }
    }
}

// ---------------------------------------------------------------------------
// Kernel 3: output projection.
// out[b,s,o] = sum_i conc[b,s,i] * Wo[o,i] + bo[o]
// conc[b,s,h*D+d] = ctx[((b*H+h)*S+s)*D+d]
// M = B*S = 8192, N = E = 1024, K = E = 1024.
// ---------------------------------------------------------------------------
__global__ __launch_bounds__(256) void proj_kernel(
    const float* __restrict__ ctx,  // [B,H,S,D]
    const float* __restrict__ Wo,   // [E,E] row-major [out,in]
    const float* __restrict__ bo,   // [E]
    float* __restrict__ out)        // [B,S,E]
{
    const int mtile = blockIdx.x;   // 0..127
    const int ntile = blockIdx.y;   // 0..15
    const int tid = threadIdx.x;
    const int tx = tid % 16, ty = tid / 16;

    __shared__ float As[64][33];   // conc tile: 64 m x 32 k
    __shared__ float Bs[64][33];   // Wo tile:   64 n x 32 k (B[n][k] = Wo[n][k])

    const int m0 = mtile * 64;
    const int n0 = ntile * 64;
    float acc[4][4] = {};

    for (int k0 = 0; k0 < En; k0 += 32) {
        const int h = k0 / Dn;       // 32 | k0 so the k-chunk stays within a head
        const int dbase = k0 % Dn;
        #pragma unroll
        for (int i = 0; i < 8; i++) {
            int idx = tid + i * 256;
            int r = idx / 32, c = idx % 32;
            int m = m0 + r;
            int b = m / Sn, s = m % Sn;
            As[r][c] = ctx[(((size_t)(b * Hn + h)) * Sn + s) * Dn + dbase + c];
        }
        #pragma unroll
        for (int i = 0; i < 8; i++) {
            int idx = tid + i * 256;
            int r = idx / 32, c = idx % 32;   // r: n offset, c: k offset
            Bs[r][c] = Wo[(size_t)(n0 + r) * En + k0 + c];
        }
        __syncthreads();
        #pragma unroll
        for (int k = 0; k < 32; k++) {
            float a[4], bb[4];
            #pragma unroll
            for (int i = 0; i < 4; i++) a[i] = As[ty * 4 + i][k];
            #pragma unroll
            for (int j = 0; j < 4; j++) bb[j] = Bs[tx * 4 + j][k];
            #pragma unroll
            for (int i = 0; i < 4; i++)
                #pragma unroll
                for (int j = 0; j < 4; j++)
                    acc[i][j] += a[i] * bb[j];
        }
        __syncthreads();
    }

    #pragma unroll
    for (int i = 0; i < 4; i++) {
        int m = m0 + ty * 4 + i;
        int b = m / Sn, s = m % Sn;
        #pragma unroll
        for (int j = 0; j < 4; j++) {
            int n = n0 + tx * 4 + j;
            out[((size_t)b * Sn + s) * En + n] = acc[i][j] + bo[n];
        }
    }
}

// ---------------------------------------------------------------------------
extern "C" void kernel_launch(void* const* d_in, const int* in_sizes, int n_in,
                              void* d_out, int out_size, void* d_ws, size_t ws_size,
                              hipStream_t stream) {
    const float* x  = (const float*)d_in[0];
    const float* Wq = (const float*)d_in[1];
    const float* bq = (const float*)d_in[2];
    const float* Wk = (const float*)d_in[3];
    const float* bk = (const float*)d_in[4];
    const float* Wv = (const float*)d_in[5];
    const float* bv = (const float*)d_in[6];
    const float* Wo = (const float*)d_in[7];
    const float* bo = (const float*)d_in[8];
    float* out = (float*)d_out;

    float* ws = (float*)d_ws;
    const size_t QSZ = (size_t)Bn * Hn * Sn * Dn;  // 8,388,608 floats
    float* Qb = ws;
    float* Kb = ws + QSZ;
    float* Vb = ws + 2 * QSZ;
    float* Cb = ws + 3 * QSZ;

    qkv_kernel<<<dim3(Sn / 64, Hn, Bn * 3), 256, 0, stream>>>(
        x, Wq, bq, Wk, bk, Wv, bv, Qb, Kb, Vb);
    attn_kernel<<<dim3(Sn / 64, Bn * Hn), 256, 0, stream>>>(Qb, Kb, Vb, Cb);
    proj_kernel<<<dim3((Bn * Sn) / 64, En / 64), 256, 0, stream>>>(Cb, Wo, bo, out);
}

// Round 3
// 470.926 us; speedup vs baseline: 6.9821x; 6.9821x over previous
//
#include <hip/hip_runtime.h>
#include <math.h>

// B=4, S=2048, E=1024, H=16, D=64
constexpr int Bn = 4;
constexpr int Sn = 2048;
constexpr int En = 1024;
constexpr int Hn = 16;
constexpr int Dn = 64;

typedef float f32x4 __attribute__((ext_vector_type(4)));
typedef short s16x8 __attribute__((ext_vector_type(8)));
typedef short s16x4 __attribute__((ext_vector_type(4)));

__device__ __forceinline__ short f2bf(float f) {
    unsigned u = __builtin_bit_cast(unsigned, f);
    unsigned r = (u + 0x7fffu + ((u >> 16) & 1u)) >> 16;
    return (short)r;
}

// ---------------------------------------------------------------------------
// Conversion kernels
// ---------------------------------------------------------------------------
__global__ __launch_bounds__(256) void conv_x_kernel(
    const float* __restrict__ x, short* __restrict__ y)
{
    // 8,388,608 elements, 4 per thread
    size_t i = ((size_t)blockIdx.x * 256 + threadIdx.x) * 4;
    float4 v = *(const float4*)(x + i);
    s16x4 o;
    o[0] = f2bf(v.x); o[1] = f2bf(v.y); o[2] = f2bf(v.z); o[3] = f2bf(v.w);
    *(s16x4*)(y + i) = o;
}

// Build Wcat[n][k] bf16 (n = p*1024 + h*64 + d, k = e) and bias_cat[n].
__global__ __launch_bounds__(256) void build_wcat_kernel(
    const float* __restrict__ Wq, const float* __restrict__ bq,
    const float* __restrict__ Wk, const float* __restrict__ bk,
    const float* __restrict__ Wv, const float* __restrict__ bv,
    short* __restrict__ Wcat, float* __restrict__ bias_cat)
{
    const int n = blockIdx.x;            // 0..3071
    const int p = n >> 10;
    const int h = (n >> 6) & 15;
    const int d = n & 63;
    const float* W = (p == 0) ? Wq : (p == 1) ? Wk : Wv;
    const float* bb = (p == 0) ? bq : (p == 1) ? bk : bv;
    const float* Wh = W + (size_t)h * En * Dn;
    short* dst = Wcat + (size_t)n * En;
    #pragma unroll
    for (int i = 0; i < 4; i++) {
        int k = threadIdx.x + i * 256;
        dst[k] = f2bf(Wh[(size_t)k * Dn + d]);
    }
    if (threadIdx.x == 0) bias_cat[n] = bb[h * Dn + d];
}

__global__ __launch_bounds__(256) void conv_wo_kernel(
    const float* __restrict__ Wo, short* __restrict__ Wob)
{
    const size_t base = (size_t)blockIdx.x * En;
    #pragma unroll
    for (int i = 0; i < 4; i++) {
        int k = threadIdx.x + i * 256;
        Wob[base + k] = f2bf(Wo[base + k]);
    }
}

// ---------------------------------------------------------------------------
// bf16 MFMA GEMM: C[M x N] = A[M x 1024] @ Bt[N x 1024]^T (+ bias)
// 128x128 tile, BK=32, 4 waves (2x2), each wave 64x64 = 4x4 MFMA subtiles.
// mode 0: out fp32 [M x N] += bo bias   (output projection)
// mode 1: QKV epilogue: n = p*1024+h*64+d; writes bf16 Q[b,h,s,d], K[b,h,s,d],
//         Vt[b,h,d,s]; bias from bias_cat[n].
// ---------------------------------------------------------------------------
__global__ __launch_bounds__(256) void gemm_bt_kernel(
    const short* __restrict__ A,   // [M][1024] bf16
    const short* __restrict__ Bt,  // [N][1024] bf16
    const float* __restrict__ bias,
    float* __restrict__ outF,
    short* __restrict__ Qb, short* __restrict__ Kb, short* __restrict__ Vtb,
    int mode)
{
    constexpr int K = En;
    constexpr int PITCH = 40;   // shorts; 80 B, 16B-aligned rows
    const int m0 = blockIdx.x * 128;
    const int n0 = blockIdx.y * 128;

    __shared__ short As[128 * PITCH];
    __shared__ short Bs[128 * PITCH];

    const int tid  = threadIdx.x;
    const int w    = tid >> 6;
    const int lane = tid & 63;
    const int quad = lane >> 4;
    const int l15  = lane & 15;
    const int wr = (w >> 1) * 64;
    const int wc = (w & 1) * 64;

    f32x4 acc[4][4];
    #pragma unroll
    for (int i = 0; i < 4; i++)
        #pragma unroll
        for (int j = 0; j < 4; j++)
            #pragma unroll
            for (int e = 0; e < 4; e++) acc[i][j][e] = 0.f;

    for (int k0 = 0; k0 < K; k0 += 32) {
        // stage A and Bt tiles: 128 rows x 32 k each; thread does 2 groups/array
        #pragma unroll
        for (int rep = 0; rep < 2; rep++) {
            int g = tid + rep * 256;
            int row = g >> 2, part = (g & 3) * 8;
            *(s16x8*)&As[row * PITCH + part] =
                *(const s16x8*)(A + (size_t)(m0 + row) * K + k0 + part);
            *(s16x8*)&Bs[row * PITCH + part] =
                *(const s16x8*)(Bt + (size_t)(n0 + row) * K + k0 + part);
        }
        __syncthreads();

        s16x8 af[4], bfr[4];
        #pragma unroll
        for (int mt = 0; mt < 4; mt++)
            af[mt] = *(const s16x8*)&As[(wr + mt * 16 + l15) * PITCH + quad * 8];
        #pragma unroll
        for (int nt = 0; nt < 4; nt++)
            bfr[nt] = *(const s16x8*)&Bs[(wc + nt * 16 + l15) * PITCH + quad * 8];
        #pragma unroll
        for (int mt = 0; mt < 4; mt++)
            #pragma unroll
            for (int nt = 0; nt < 4; nt++)
                acc[mt][nt] = __builtin_amdgcn_mfma_f32_16x16x32_bf16(
                    af[mt], bfr[nt], acc[mt][nt], 0, 0, 0);
        __syncthreads();
    }

    // epilogue
    if (mode == 0) {
        #pragma unroll
        for (int mt = 0; mt < 4; mt++) {
            #pragma unroll
            for (int reg = 0; reg < 4; reg++) {
                int m = m0 + wr + mt * 16 + quad * 4 + reg;
                #pragma unroll
                for (int nt = 0; nt < 4; nt++) {
                    int n = n0 + wc + nt * 16 + l15;
                    outF[(size_t)m * En + n] = acc[mt][nt][reg] + bias[n];
                }
            }
        }
    } else {
        const int p = (n0 + wc) >> 10;   // uniform over 64-wide wave tile
        #pragma unroll
        for (int mt = 0; mt < 4; mt++) {
            #pragma unroll
            for (int reg = 0; reg < 4; reg++) {
                int m = m0 + wr + mt * 16 + quad * 4 + reg;
                int b = m >> 11, s = m & 2047;
                #pragma unroll
                for (int nt = 0; nt < 4; nt++) {
                    int n = n0 + wc + nt * 16 + l15;
                    int h = (n >> 6) & 15, d = n & 63;
                    short v = f2bf(acc[mt][nt][reg] + bias[n]);
                    if (p == 0)
                        Qb[(((size_t)(b * Hn + h)) * Sn + s) * Dn + d] = v;
                    else if (p == 1)
                        Kb[(((size_t)(b * Hn + h)) * Sn + s) * Dn + d] = v;
                    else
                        Vtb[(((size_t)(b * Hn + h)) * Dn + d) * Sn + s] = v;
                }
            }
        }
    }
}

// ---------------------------------------------------------------------------
// Flash attention, bf16 MFMA. Block = 4 waves, 64 q-rows per block.
// Q[b,h,s,d], K[b,h,s,d], Vt[b,h,d,s] bf16; output conc bf16 [b,s,h*64+d].
// ---------------------------------------------------------------------------
__global__ __launch_bounds__(256) void attn_mfma_kernel(
    const short* __restrict__ Q, const short* __restrict__ K,
    const short* __restrict__ Vt, short* __restrict__ Cb)
{
    constexpr int PITCH = 72;   // shorts; 144 B rows, 16B-aligned
    const int qt = blockIdx.x;  // 0..31
    const int bh = blockIdx.y;  // 0..63
    const int b = bh >> 4, h = bh & 15;

    __shared__ short Ks[64 * PITCH];
    __shared__ short Vts[64 * PITCH];
    __shared__ short Ps[64 * PITCH];

    const int tid  = threadIdx.x;
    const int w    = tid >> 6;
    const int lane = tid & 63;
    const int quad = lane >> 4;
    const int l15  = lane & 15;

    const short* Qp = Q + ((size_t)bh * Sn + qt * 64) * Dn;
    const short* Kp = K + (size_t)bh * Sn * Dn;
    const short* Vp = Vt + (size_t)bh * Dn * Sn;

    // Q fragments in registers (rows w*16+l15, k = kstep*32 + quad*8 + j)
    s16x8 aq[2];
    #pragma unroll
    for (int ks = 0; ks < 2; ks++)
        aq[ks] = *(const s16x8*)(Qp + (size_t)(w * 16 + l15) * Dn + ks * 32 + quad * 8);

    f32x4 acc[4];
    #pragma unroll
    for (int nt = 0; nt < 4; nt++)
        #pragma unroll
        for (int e = 0; e < 4; e++) acc[nt][e] = 0.f;
    float mrow[4], lrow[4];
    #pragma unroll
    for (int r = 0; r < 4; r++) { mrow[r] = -1e30f; lrow[r] = 0.f; }

    const float scale = 0.125f;
    const int qrow_base = qt * 64 + w * 16 + quad * 4;   // + reg

    for (int kt = 0; kt <= qt; kt++) {
        // stage K tile [64 kv][64 d] and Vt tile [64 d][64 kv]
        #pragma unroll
        for (int rep = 0; rep < 2; rep++) {
            int g = tid + rep * 256;
            int row = g >> 3, part = (g & 7) * 8;
            *(s16x8*)&Ks[row * PITCH + part] =
                *(const s16x8*)(Kp + (size_t)(kt * 64 + row) * Dn + part);
            *(s16x8*)&Vts[row * PITCH + part] =
                *(const s16x8*)(Vp + (size_t)row * Sn + kt * 64 + part);
        }
        __syncthreads();

        // scores: S = Q @ K^T  (rows q, cols kv)
        f32x4 sacc[4];
        #pragma unroll
        for (int nt = 0; nt < 4; nt++)
            #pragma unroll
            for (int e = 0; e < 4; e++) sacc[nt][e] = 0.f;
        #pragma unroll
        for (int ks = 0; ks < 2; ks++) {
            #pragma unroll
            for (int nt = 0; nt < 4; nt++) {
                s16x8 bk = *(const s16x8*)&Ks[(nt * 16 + l15) * PITCH + ks * 32 + quad * 8];
                sacc[nt] = __builtin_amdgcn_mfma_f32_16x16x32_bf16(
                    aq[ks], bk, sacc[nt], 0, 0, 0);
            }
        }

        // scale + causal mask
        const int kcol_base = kt * 64 + l15;   // + nt*16
        #pragma unroll
        for (int nt = 0; nt < 4; nt++) {
            #pragma unroll
            for (int reg = 0; reg < 4; reg++) {
                float v = sacc[nt][reg] * scale;
                if (kcol_base + nt * 16 > qrow_base + reg) v = -1e30f;
                sacc[nt][reg] = v;
            }
        }

        // online softmax per row (row = quad*4+reg; reduce across 16 lanes)
        float alpha[4];
        #pragma unroll
        for (int reg = 0; reg < 4; reg++) {
            float rmax = fmaxf(fmaxf(sacc[0][reg], sacc[1][reg]),
                               fmaxf(sacc[2][reg], sacc[3][reg]));
            #pragma unroll
            for (int off = 1; off < 16; off <<= 1)
                rmax = fmaxf(rmax, __shfl_xor(rmax, off));
            float mnew = fmaxf(mrow[reg], rmax);
            alpha[reg] = __expf(mrow[reg] - mnew);
            mrow[reg] = mnew;
            float rs = 0.f;
            #pragma unroll
            for (int nt = 0; nt < 4; nt++) {
                float pv = __expf(sacc[nt][reg] - mnew);
                Ps[(w * 16 + quad * 4 + reg) * PITCH + nt * 16 + l15] = f2bf(pv);
                rs += pv;
            }
            #pragma unroll
            for (int off = 1; off < 16; off <<= 1)
                rs += __shfl_xor(rs, off);
            lrow[reg] = lrow[reg] * alpha[reg] + rs;
        }
        #pragma unroll
        for (int nt = 0; nt < 4; nt++)
            #pragma unroll
            for (int reg = 0; reg < 4; reg++)
                acc[nt][reg] *= alpha[reg];

        // PV: O += P[64q x 64kv] @ V[64kv x 64d]
        // (Ps written/read within the same wave's rows; no cross-wave dep)
        #pragma unroll
        for (int ks = 0; ks < 2; ks++) {
            s16x8 ap = *(const s16x8*)&Ps[(w * 16 + l15) * PITCH + ks * 32 + quad * 8];
            #pragma unroll
            for (int nt = 0; nt < 4; nt++) {
                s16x8 bv = *(const s16x8*)&Vts[(nt * 16 + l15) * PITCH + ks * 32 + quad * 8];
                acc[nt] = __builtin_amdgcn_mfma_f32_16x16x32_bf16(
                    ap, bv, acc[nt], 0, 0, 0);
            }
        }
        __syncthreads();
    }

    // epilogue: conc[b][s][h*64+d] bf16
    #pragma unroll
    for (int reg = 0; reg < 4; reg++) {
        int s = qt * 64 + w * 16 + quad * 4 + reg;
        float inv = 1.f / lrow[reg];
        #pragma unroll
        for (int nt = 0; nt < 4; nt++) {
            int d = nt * 16 + l15;
            Cb[((size_t)(b * Sn + s)) * En + h * Dn + d] = f2bf(acc[nt][reg] * inv);
        }
    }
}

// ---------------------------------------------------------------------------
extern "C" void kernel_launch(void* const* d_in, const int* in_sizes, int n_in,
                              void* d_out, int out_size, void* d_ws, size_t ws_size,
                              hipStream_t stream) {
    const float* x  = (const float*)d_in[0];
    const float* Wq = (const float*)d_in[1];
    const float* bq = (const float*)d_in[2];
    const float* Wk = (const float*)d_in[3];
    const float* bk = (const float*)d_in[4];
    const float* Wv = (const float*)d_in[5];
    const float* bv = (const float*)d_in[6];
    const float* Wo = (const float*)d_in[7];
    const float* bo = (const float*)d_in[8];
    float* out = (float*)d_out;

    // workspace layout (shorts unless noted)
    const size_t XS   = (size_t)Bn * Sn * En;       // 8,388,608
    const size_t WCS  = (size_t)3 * En * Hn * Dn;   // 3,145,728
    const size_t WOS  = (size_t)En * En;            // 1,048,576
    const size_t QSZ  = (size_t)Bn * Hn * Sn * Dn;  // 8,388,608

    short* Ax    = (short*)d_ws;
    short* Wcat  = Ax + XS;
    short* Wob   = Wcat + WCS;
    float* biasc = (float*)(Wob + WOS);
    short* Qb    = (short*)(biasc + 3072);
    short* Kb    = Qb + QSZ;
    short* Vtb   = Kb + QSZ;
    short* Cbf   = Vtb + QSZ;

    conv_x_kernel<<<dim3(XS / (256 * 4)), 256, 0, stream>>>(x, Ax);
    build_wcat_kernel<<<dim3(3072), 256, 0, stream>>>(Wq, bq, Wk, bk, Wv, bv,
                                                      Wcat, biasc);
    conv_wo_kernel<<<dim3(En), 256, 0, stream>>>(Wo, Wob);

    // QKV: [8192 x 1024] @ [1024 x 3072]
    gemm_bt_kernel<<<dim3((Bn * Sn) / 128, 3072 / 128), 256, 0, stream>>>(
        Ax, Wcat, biasc, nullptr, Qb, Kb, Vtb, 1);

    attn_mfma_kernel<<<dim3(Sn / 64, Bn * Hn), 256, 0, stream>>>(Qb, Kb, Vtb, Cbf);

    // out: [8192 x 1024] @ Wo^T + bo
    gemm_bt_kernel<<<dim3((Bn * Sn) / 128, En / 128), 256, 0, stream>>>(
        Cbf, Wob, bo, out, nullptr, nullptr, nullptr, 0);
}